// Round 3
// baseline (701.126 us; speedup 1.0000x reference)
//
#include <hip/hip_runtime.h>
#include <hip/hip_bf16.h>

// GraphSageLayer on MI355X. B=4, N=4096, D_IN=REP=D_OUT=128.
// proj (nodes->3 reps, bf16) -> agg (adj @ in_rep, adj^T @ out_rep) -> final (concat @ W_upd^T, tanh).
//
// R3: barrier-free agg. R2 evidence: 83% stall, HBM 25%, MfmaUtil 7.5% --
// the vmcnt(0)+s_barrier per epoch serialized HBM and compute. New agg:
//  - !TC half: NO LDS. adj B-frags loaded directly from global (lane n=i row,
//    k=8 consecutive j = 2 dwordx4, full 128B line per row). Wave owns 16
//    exclusive i rows x 128 v x full k. 2-deep register prefetch, no syncs.
//  - TC half: wave-PRIVATE double-buffered LDS tile (32i x 32j) for the
//    transpose; ordering via wave-local lgkmcnt only, no __syncthreads.
//    Wave owns 32 i rows (128B-line aligned ownership).
// Waves drift freely -> HBM queue never drains (each wave keeps ~10KB in
// flight; 6 waves/CU avg).

typedef __attribute__((ext_vector_type(8))) short short8;
typedef __attribute__((ext_vector_type(4))) float f32x4;
typedef __attribute__((ext_vector_type(4))) unsigned short u16x4;

#define MFMA(a, b, c) __builtin_amdgcn_mfma_f32_16x16x32_bf16(a, b, c, 0, 0, 0)

__device__ __forceinline__ unsigned short f2bf(float x) {
  union { float f; unsigned u; } v; v.f = x;
  unsigned r = v.u + 0x7FFFu + ((v.u >> 16) & 1u);   // RNE to bf16
  return (unsigned short)(r >> 16);
}

__device__ __forceinline__ short8 pack8(float4 a, float4 b) {
  short8 v;
  v[0] = (short)f2bf(a.x); v[1] = (short)f2bf(a.y); v[2] = (short)f2bf(a.z); v[3] = (short)f2bf(a.w);
  v[4] = (short)f2bf(b.x); v[5] = (short)f2bf(b.y); v[6] = (short)f2bf(b.z); v[7] = (short)f2bf(b.w);
  return v;
}

// ---------------------------------------------------------------------------
// Kernel 1: projections. rep = elu(nodes @ W^T + b). grid=(256 m-tiles, 3).
// ---------------------------------------------------------------------------
__global__ __launch_bounds__(256) void proj_kernel(
    const float* __restrict__ nodes,   // [16384][128]
    const float* __restrict__ W_in, const float* __restrict__ b_in,
    const float* __restrict__ W_out, const float* __restrict__ b_out,
    const float* __restrict__ W_node, const float* __restrict__ b_node,
    unsigned short* __restrict__ in_rep_t,   // [4][128][4096]
    unsigned short* __restrict__ out_rep_t,  // [4][128][4096]
    unsigned short* __restrict__ node_rep)   // [4][4096][128]
{
  const int wsel = blockIdx.y;
  const float* W    = (wsel == 0) ? W_in  : (wsel == 1) ? W_out  : W_node;
  const float* bias = (wsel == 0) ? b_in  : (wsel == 1) ? b_out  : b_node;

  const int tid  = threadIdx.x;
  const int lane = tid & 63;
  const int w    = tid >> 6;
  const int q    = lane >> 4;
  const int r15  = lane & 15;
  const int m0   = blockIdx.x * 64 + w * 16;

  f32x4 acc[8];
#pragma unroll
  for (int nt = 0; nt < 8; ++nt) acc[nt] = (f32x4)0.0f;

  short8 a[4];
#pragma unroll
  for (int ks = 0; ks < 4; ++ks) {
    const float* p = nodes + (size_t)(m0 + r15) * 128 + ks * 32 + q * 8;
    a[ks] = pack8(*(const float4*)p, *(const float4*)(p + 4));
  }

#pragma unroll
  for (int ks = 0; ks < 4; ++ks)
#pragma unroll
    for (int nt = 0; nt < 8; ++nt) {
      const float* p = W + (size_t)(nt * 16 + r15) * 128 + ks * 32 + q * 8;
      short8 bv = pack8(*(const float4*)p, *(const float4*)(p + 4));
      acc[nt] = MFMA(a[ks], bv, acc[nt]);
    }

#pragma unroll
  for (int nt = 0; nt < 8; ++nt) {
    const int rcol = nt * 16 + r15;
    const float bv = bias[rcol];
    const int g0 = m0 + q * 4;
    float x[4];
#pragma unroll
    for (int c = 0; c < 4; ++c) {
      float t = acc[nt][c] + bv;
      x[c] = (t > 0.f) ? t : (expf(t) - 1.f);   // ELU
    }
    if (wsel < 2) {
      unsigned short* rep = (wsel == 0) ? in_rep_t : out_rep_t;
      const int b = g0 >> 12, j = g0 & 4095;
      u16x4 o;
#pragma unroll
      for (int c = 0; c < 4; ++c) o[c] = f2bf(x[c]);
      *(u16x4*)&rep[((size_t)b << 19) + (size_t)rcol * 4096 + j] = o;
    } else {
#pragma unroll
      for (int c = 0; c < 4; ++c)
        node_rep[(size_t)(g0 + c) * 128 + rcol] = f2bf(x[c]);
    }
  }
}

// ---------------------------------------------------------------------------
// Kernel 2: aggregations, barrier-free. Grid = 384 blocks x 256 thr:
//   blocks [0,128):   TC  (out_agg = adj^T @ out_rep), wave = 32 i x 128 v
//   blocks [128,384): !TC (in_agg  = adj   @ in_rep),  wave = 16 i x 128 v
// MFMA: A = rep_t[v][j] (bf16 direct global, L2-hot), B = adj frags.
// D: row(m=v)=quad*4+reg, col(n=i)=lane&15 -> agg[b][i][v0..3] 8B store.
// ---------------------------------------------------------------------------
#define TCT_ST 40              // shorts per private-tile row (80 B, 16B-aligned)
#define TCT_SZ (32 * TCT_ST)   // one buffer: 32 i-rows

__global__ __launch_bounds__(256) void agg_kernel(
    const float* __restrict__ adj,
    const unsigned short* __restrict__ in_rep_t,
    const unsigned short* __restrict__ out_rep_t,
    unsigned short* __restrict__ in_agg,
    unsigned short* __restrict__ out_agg)
{
  __shared__ unsigned short tl[4][2][TCT_SZ];   // 20 KB; TC blocks only

  const int tid  = threadIdx.x;
  const int lane = tid & 63;
  const int w    = tid >> 6;
  const int q    = lane >> 4;
  const int r15  = lane & 15;
  const int id   = blockIdx.x;

  if (id < 128) {
    // ---------------- TC: out_agg[i,v] = sum_j adj[j,i] * out_rep[j,v] ------
    const int b  = id >> 5;
    const int i0 = (id & 31) * 128 + w * 32;
    const float* adjb = adj + ((size_t)b << 24);
    const unsigned short* rep = out_rep_t + ((size_t)b << 19);
    unsigned short* aggp = out_agg + ((size_t)b << 19);
    unsigned short* tile = &tl[w][0][0];

    const unsigned short* arow[8];
#pragma unroll
    for (int mt = 0; mt < 8; ++mt)
      arow[mt] = rep + (size_t)(mt * 16 + r15) * 4096 + q * 8;

    const int jp = 2 * (lane & 15);      // j-pair base within 32-j chunk
    const int ic = (lane >> 4) * 8;      // i sub-base {0,8,16,24}
    const float* ap = adjb + (size_t)jp * 4096 + i0 + ic;

    f32x4 acc[8][2];
#pragma unroll
    for (int mt = 0; mt < 8; ++mt) { acc[mt][0] = (f32x4)0.0f; acc[mt][1] = (f32x4)0.0f; }

    float4 rr[2][4];     // raw adj rows: tile t lives in rr[t&1]
    short8 pa[2][8];     // A-frags: A(t) in pa[t&1]

    auto gload_adj = [&](int t, float4* d) {
      const float* p = ap + (size_t)t * 32 * 4096;
      d[0] = *(const float4*)p;          d[1] = *(const float4*)(p + 4);
      d[2] = *(const float4*)(p + 4096); d[3] = *(const float4*)(p + 4100);
    };
    auto gload_a = [&](int t, short8* d) {
#pragma unroll
      for (int mt = 0; mt < 8; ++mt) d[mt] = *(const short8*)(arow[mt] + t * 32);
    };
    auto pack_tile = [&](const float4* r, unsigned short* dst) {
      const float* r0 = (const float*)&r[0];   // row jp,   8 floats
      const float* r1 = (const float*)&r[2];   // row jp+1, 8 floats
#pragma unroll
      for (int c = 0; c < 8; ++c) {
        unsigned v = (unsigned)f2bf(r0[c]) | ((unsigned)f2bf(r1[c]) << 16);
        *(unsigned*)&dst[(ic + c) * TCT_ST + jp] = v;
      }
    };

    // prologue: tile0 -> rr[0] -> buf0; tile1 -> rr[1]; A0,A1
    gload_adj(0, rr[0]);
    gload_a(0, pa[0]);
    gload_adj(1, rr[1]);
    gload_a(1, pa[1]);
    pack_tile(rr[0], tile);             // buf 0

#pragma unroll 2
    for (int e = 0; e < 128; ++e) {
      const int cur = e & 1, nxt = cur ^ 1;
      // 1. B-frags for tile e from buf[cur] (written iter e-1 / prologue)
      short8 bf[2];
#pragma unroll
      for (int nt = 0; nt < 2; ++nt)
        bf[nt] = *(const short8*)&tile[cur * TCT_SZ + (nt * 16 + r15) * TCT_ST + q * 8];
      // 2. stage tile e+1 into buf[nxt]
      if (e < 127) pack_tile(rr[nxt], tile + nxt * TCT_SZ);
      // 3. prefetch tile e+2 into the slot just freed
      if (e < 126) gload_adj(e + 2, rr[cur]);
      // 4. MFMA
#pragma unroll
      for (int mt = 0; mt < 8; ++mt) {
        acc[mt][0] = MFMA(pa[cur][mt], bf[0], acc[mt][0]);
        acc[mt][1] = MFMA(pa[cur][mt], bf[1], acc[mt][1]);
      }
      // 5. prefetch A(e+2)
      if (e < 126) gload_a(e + 2, pa[cur]);
    }

#pragma unroll
    for (int mt = 0; mt < 8; ++mt)
#pragma unroll
      for (int nt = 0; nt < 2; ++nt) {
        const int i  = i0 + nt * 16 + r15;
        const int v0 = mt * 16 + q * 4;
        u16x4 o;
#pragma unroll
        for (int c = 0; c < 4; ++c) o[c] = f2bf(acc[mt][nt][c]);
        *(u16x4*)&aggp[(size_t)i * 128 + v0] = o;
      }
  } else {
    // ---------------- !TC: in_agg[i,v] = sum_j adj[i,j] * in_rep[j,v] ------
    const int t  = id - 128;
    const int b  = t >> 6;
    const int i0 = (t & 63) * 64 + w * 16;
    const float* adjb = adj + ((size_t)b << 24);
    const unsigned short* rep = in_rep_t + ((size_t)b << 19);
    unsigned short* aggp = in_agg + ((size_t)b << 19);

    const unsigned short* arow[8];
#pragma unroll
    for (int mt = 0; mt < 8; ++mt)
      arow[mt] = rep + (size_t)(mt * 16 + r15) * 4096 + q * 8;

    const float* ap = adjb + (size_t)(i0 + r15) * 4096 + q * 8;

    f32x4 acc[8];
#pragma unroll
    for (int mt = 0; mt < 8; ++mt) acc[mt] = (f32x4)0.0f;

    float4 rr[2][2];     // raw adj: tile t in rr[t&1]
    short8 pa[2][8];

    auto gload_adj = [&](int t_, float4* d) {
      const float* p = ap + t_ * 32;
      d[0] = *(const float4*)p; d[1] = *(const float4*)(p + 4);
    };
    auto gload_a = [&](int t_, short8* d) {
#pragma unroll
      for (int mt = 0; mt < 8; ++mt) d[mt] = *(const short8*)(arow[mt] + t_ * 32);
    };

    gload_adj(0, rr[0]);
    gload_a(0, pa[0]);
    gload_adj(1, rr[1]);
    gload_a(1, pa[1]);

#pragma unroll 2
    for (int e = 0; e < 128; ++e) {
      const int cur = e & 1;
      short8 bf = pack8(rr[cur][0], rr[cur][1]);   // B: adj[i0+r15][e*32+q*8..]
      if (e < 126) gload_adj(e + 2, rr[cur]);
#pragma unroll
      for (int mt = 0; mt < 8; ++mt)
        acc[mt] = MFMA(pa[cur][mt], bf, acc[mt]);
      if (e < 126) gload_a(e + 2, pa[cur]);
    }

#pragma unroll
    for (int mt = 0; mt < 8; ++mt) {
      const int i  = i0 + r15;
      const int v0 = mt * 16 + q * 4;
      u16x4 o;
#pragma unroll
      for (int c = 0; c < 4; ++c) o[c] = f2bf(acc[mt][c]);
      *(u16x4*)&aggp[(size_t)i * 128 + v0] = o;
    }
  }
}

// ---------------------------------------------------------------------------
// Kernel 3: out[n,o] = tanh(sum_k upd[n,k] * W_upd[o,k] + b_upd[o]),
// upd = concat(in_agg, node_rep, out_agg). grid=512 (n-tile 32).
// ---------------------------------------------------------------------------
__global__ __launch_bounds__(256) void final_kernel(
    const unsigned short* __restrict__ in_agg,    // [16384][128]
    const unsigned short* __restrict__ node_rep,  // [16384][128]
    const unsigned short* __restrict__ out_agg,   // [16384][128]
    const float* __restrict__ W_upd,              // [128][384]
    const float* __restrict__ b_upd,              // [128]
    float* __restrict__ out)                      // [16384][128]
{
  const int tid  = threadIdx.x;
  const int lane = tid & 63;
  const int w    = tid >> 6;
  const int q    = lane >> 4;
  const int r15  = lane & 15;
  const int n0   = blockIdx.x * 32;

  const unsigned short* srcs[3] = { in_agg, node_rep, out_agg };

  f32x4 acc[2][2];
#pragma unroll
  for (int mt = 0; mt < 2; ++mt)
#pragma unroll
    for (int nt = 0; nt < 2; ++nt) acc[mt][nt] = (f32x4)0.0f;

#pragma unroll
  for (int ks = 0; ks < 12; ++ks) {
    const unsigned short* src = srcs[ks >> 2];
    const int col0 = (ks & 3) * 32 + q * 8;
    short8 a[2];
#pragma unroll
    for (int mt = 0; mt < 2; ++mt) {
      const float* p = W_upd + (size_t)(w * 32 + mt * 16 + r15) * 384 + ks * 32 + q * 8;
      a[mt] = pack8(*(const float4*)p, *(const float4*)(p + 4));
    }
#pragma unroll
    for (int nt = 0; nt < 2; ++nt) {
      const int g = n0 + nt * 16 + r15;
      short8 bv = *(const short8*)&src[(size_t)g * 128 + col0];
      acc[0][nt] = MFMA(a[0], bv, acc[0][nt]);
      acc[1][nt] = MFMA(a[1], bv, acc[1][nt]);
    }
  }

#pragma unroll
  for (int mt = 0; mt < 2; ++mt) {
    const int o0 = w * 32 + mt * 16 + q * 4;
#pragma unroll
    for (int nt = 0; nt < 2; ++nt) {
      const int g = n0 + nt * 16 + r15;
      f32x4 ov;
#pragma unroll
      for (int c = 0; c < 4; ++c) ov[c] = tanhf(acc[mt][nt][c] + b_upd[o0 + c]);
      *(f32x4*)&out[(size_t)g * 128 + o0] = ov;
    }
  }
}

// ---------------------------------------------------------------------------
extern "C" void kernel_launch(void* const* d_in, const int* in_sizes, int n_in,
                              void* d_out, int out_size, void* d_ws, size_t ws_size,
                              hipStream_t stream) {
  (void)in_sizes; (void)n_in; (void)out_size; (void)ws_size;
  const float* nodes  = (const float*)d_in[0];
  const float* adj    = (const float*)d_in[1];
  const float* W_in   = (const float*)d_in[2];
  const float* b_in   = (const float*)d_in[3];
  const float* W_out  = (const float*)d_in[4];
  const float* b_out  = (const float*)d_in[5];
  const float* W_node = (const float*)d_in[6];
  const float* b_node = (const float*)d_in[7];
  const float* W_upd  = (const float*)d_in[8];
  const float* b_upd  = (const float*)d_in[9];
  float* out = (float*)d_out;

  unsigned short* ws = (unsigned short*)d_ws;
  const size_t SZ = (size_t)4 * 128 * 4096;
  unsigned short* in_rep_t  = ws;
  unsigned short* out_rep_t = ws + SZ;
  unsigned short* node_rep  = ws + 2 * SZ;
  unsigned short* in_agg    = ws + 3 * SZ;
  unsigned short* out_agg   = ws + 4 * SZ;

  proj_kernel<<<dim3(256, 3), 256, 0, stream>>>(
      nodes, W_in, b_in, W_out, b_out, W_node, b_node,
      in_rep_t, out_rep_t, node_rep);
  agg_kernel<<<384, 256, 0, stream>>>(adj, in_rep_t, out_rep_t, in_agg, out_agg);
  final_kernel<<<512, 256, 0, stream>>>(in_agg, node_rep, out_agg, W_upd, b_upd, out);
}